// Round 6
// baseline (2499.507 us; speedup 1.0000x reference)
//
#include <hip/hip_runtime.h>

// ---------------------------------------------------------------------------
// FusedExpertsNetwork: y = relu(x @ W1^T + b1) @ W2 + b2, per expert.
// E=8, C=4096, M=1024, H=4096, O=1024. Inputs fp32; compute bf16 MFMA.
//
// R6: read-ahead software pipeline. R4/R5 counters fit phase = MFMA +
// LDS-read + stage + barrier as a strict SERIAL SUM (1511 pred / 1520 meas;
// 2718 / 2690): barrier-lockstep + in-phase RAW made LDS and matrix pipes
// mutually exclusive. Fix: each phase's ds_reads load the NEXT phase's
// fragments (ping-pong afP/afQ, bwP/bwQ); MFMA consumes last phase's regs,
// so it has no lgkm dependency and the LDS drain hides under the MFMA.
//
// Iter = 2 K-tiles (U=buf0, V=U+1=buf1), 4 phases (reads are for phase+1):
//  P1: rd afQ<-A(U,h1);        st A1(V);        MFMA h0(U) afP*bwP; vmcnt(2)
//  P2: rd bwQ<-B(V),afP<-A0(V);st B(W)+A0(W);   MFMA h1(U) afQ*bwP; vmcnt(6)
//  P3: rd afQ<-A(V,h1);        st A1(W);        MFMA h0(V) afP*bwQ; vmcnt(2)
//  P4: rd bwP<-B(W),afP<-A0(W);st B(X)+A0(X);   MFMA h1(V) afQ*bwQ; vmcnt(6)
//  (W=U+2->buf0, X=U+3->buf1; barrier after each vmcnt)
// Ledger (periodic, verified): end-P1 outstanding [prevP4:6, P1:2] ->
// vmcnt(2) retires B,A0(V) read by P2; end-P2 [P1:2, P2:6] -> vmcnt(6)
// retires A1(V) read by P3; P3/P4 symmetric. Stage->retire ~1 phase
// (~1500cyc > 900cyc HBM). WAR: every region's read->overwrite gap is 2
// phases; phase-p reads complete before p+1 MFMA (lgkm) < any p+2 stage.
// vmcnt asm ("memory") pins all memory ops inside their phase.
// ---------------------------------------------------------------------------

typedef __bf16 bf16x8 __attribute__((ext_vector_type(8)));
typedef float f32x4 __attribute__((ext_vector_type(4)));

__device__ __forceinline__ unsigned short f2bf(float f) {
  union { float f; unsigned int u; } v; v.f = f;
  unsigned int u = v.u;
  u += 0x7fffu + ((u >> 16) & 1u);   // round-to-nearest-even
  return (unsigned short)(u >> 16);
}

#define GLD_LDS16(gptr, lptr)                                               \
  __builtin_amdgcn_global_load_lds(                                         \
      (const __attribute__((address_space(1))) void*)(gptr),                \
      (__attribute__((address_space(3))) void*)(lptr), 16, 0, 0)

// --------------------------- fp32 -> bf16 copy ------------------------------
__global__ void cvt_bf16_kernel(const float* __restrict__ in,
                                unsigned short* __restrict__ out, long n) {
  long i = ((long)blockIdx.x * blockDim.x + threadIdx.x) * 4;
  if (i >= n) return;
  const float4 v = *(const float4*)(in + i);
  ushort4 o;
  o.x = f2bf(v.x); o.y = f2bf(v.y); o.z = f2bf(v.z); o.w = f2bf(v.w);
  *(ushort4*)(out + i) = o;
}

// ------------------- fp32 (H,O) -> bf16 (O,H) transpose ---------------------
__global__ void transpose_cvt_kernel(const float* __restrict__ in,
                                     unsigned short* __restrict__ out,
                                     int H, int O, long istride, long ostride) {
  __shared__ unsigned short tile[32][33];
  const float* inp = in + (long)blockIdx.z * istride;
  unsigned short* outp = out + (long)blockIdx.z * ostride;
  const int o0 = blockIdx.x * 32, h0 = blockIdx.y * 32;
  const int tx = threadIdx.x, ty = threadIdx.y;
#pragma unroll
  for (int r = ty; r < 32; r += 8)
    tile[r][tx] = f2bf(inp[(long)(h0 + r) * O + o0 + tx]);
  __syncthreads();
#pragma unroll
  for (int r = ty; r < 32; r += 8)
    outp[(long)(o0 + r) * H + h0 + tx] = tile[tx][r];
}

// --------------------------- bf16 gemm_bt -----------------------------------
// C[m,n] = sum_k A[m,k] * B[n,k]  (+ bias[n]); EPI=0: relu -> bf16 out
//                                              EPI=1: fp32 out
// Tile 256x256, BK=64, 512 threads (8 waves, 2x4), per-wave C = 128x64.
// LDS: element (row R, k) at R*BK + ((k/8) ^ (R&7))*8 + k%8  (zero-conflict
// swizzle; staging pre-swizzles the GLOBAL k-chunk so the linear
// global_load_lds dest yields the swizzled layout).
#define BM 256
#define BN 256
#define BK 64

template <int EPI>
__global__ __launch_bounds__(512, 2) void gemm_bt_kernel(
    const unsigned short* __restrict__ A, const unsigned short* __restrict__ B,
    const float* __restrict__ bias, void* __restrict__ Cout,
    int Nd, int Kd, long sA, long sB, long sBias, long sC) {
  __shared__ unsigned short As[2][BM * BK];   // 64 KiB
  __shared__ unsigned short Bs[2][BN * BK];   // 64 KiB

  // ---- T1: XCD-aware tile swizzle (all grids have nwg % 8 == 0) ----
  const int nbx = gridDim.x;
  const int nbxy = nbx * gridDim.y;
  const int nwg = nbxy * gridDim.z;
  int gid = blockIdx.x + nbx * blockIdx.y + nbxy * blockIdx.z;
  gid = (gid & 7) * (nwg >> 3) + (gid >> 3);
  const int bz = gid / nbxy;
  const int rem = gid - bz * nbxy;
  const int by = rem / nbx;
  const int bx = rem - by * nbx;

  const unsigned short* Ae = A + (long)bz * sA;
  const unsigned short* Be = B + (long)bz * sB;
  const float* be = bias + (long)bz * sBias;

  const int tid = threadIdx.x;
  const int wave = tid >> 6;
  const int lane = tid & 63;
  const int wm = wave >> 2;   // wave row 0..1 (128 C-rows each)
  const int wn = wave & 3;    // wave col 0..3 (64 C-cols each)
  const int fr = lane & 15;   // frag row (m for A / n for B / col for D)
  const int quad = lane >> 4; // 0..3
  const int fsw = fr & 7;

  const int blockM = by * BM;
  const int blockN = bx * BN;

  // staging: one instr = 512 thr x 16B = 64 rows x 128B. tid covers row
  // band+tid/8, phys slot tid&7; global k-chunk pre-swizzled: (tid&7)^(row&7).
  const int srow = tid >> 3;                       // 0..63 within a band
  const int skc = ((tid & 7) ^ (srow & 7)) * 8;    // swizzled k elem offset
  const unsigned short* gA = Ae + (long)(blockM + srow) * Kd + skc;
  const unsigned short* gB = Be + (long)(blockN + srow) * Kd + skc;

  // LDS dest: wave-uniform base + lane*16 (HW); wave w covers rows band+w*8..+7
#define STAGE_A(buf, band, kt)                                              \
  GLD_LDS16(gA + (long)(band) * Kd + (kt) * BK,                             \
            &As[buf][(band) * BK + wave * 512])
#define STAGE_B(buf, band, kt)                                              \
  GLD_LDS16(gB + (long)(band) * Kd + (kt) * BK,                             \
            &Bs[buf][(band) * BK + wave * 512])
#define STAGE_A_MH0(buf, kt) { STAGE_A(buf, 0, kt);   STAGE_A(buf, 128, kt); }
#define STAGE_A_MH1(buf, kt) { STAGE_A(buf, 64, kt);  STAGE_A(buf, 192, kt); }
#define STAGE_B_ALL(buf, kt) { STAGE_B(buf, 0, kt);   STAGE_B(buf, 64, kt);  \
                               STAGE_B(buf, 128, kt); STAGE_B(buf, 192, kt); }

#define BAR __builtin_amdgcn_s_barrier()
#define VMCNT0 asm volatile("s_waitcnt vmcnt(0)" ::: "memory")
#define VMCNT2 asm volatile("s_waitcnt vmcnt(2)" ::: "memory")
#define VMCNT6 asm volatile("s_waitcnt vmcnt(6)" ::: "memory")

  f32x4 acc[8][4];
#pragma unroll
  for (int a = 0; a < 8; ++a)
#pragma unroll
    for (int b = 0; b < 4; ++b) acc[a][b] = (f32x4){0.f, 0.f, 0.f, 0.f};

  const int NT = Kd / BK;   // even, >= 4 for our shapes (16 and 64)

  // loop-invariant read offsets
  const int aBase = (wm * 128 + fr) * BK;
  const int bBase = (wn * 64 + fr) * BK;
  const int s0 = (quad ^ fsw) * 8;         // kk=0 slot (chunks 0..3)
  const int s1 = ((4 + quad) ^ fsw) * 8;   // kk=1 slot (chunks 4..7)

  // ping-pong fragment register sets (statically indexed; rule #20)
  bf16x8 afP[4][2], afQ[4][2], bwP[4][2], bwQ[4][2];

#define READ_AH_TO(dst, bf, h)                                              \
  {                                                                         \
    _Pragma("unroll")                                                       \
    for (int mi = 0; mi < 4; ++mi) {                                        \
      const unsigned short* _p =                                            \
          &As[bf][aBase + ((h) * 64 + mi * 16) * BK];                       \
      dst[mi][0] = *(const bf16x8*)(_p + s0);                               \
      dst[mi][1] = *(const bf16x8*)(_p + s1);                               \
    }                                                                       \
  }

#define READ_B_TO(dst, bf)                                                  \
  {                                                                         \
    _Pragma("unroll")                                                       \
    for (int ni = 0; ni < 4; ++ni) {                                        \
      const unsigned short* _p = &Bs[bf][bBase + ni * 16 * BK];             \
      dst[ni][0] = *(const bf16x8*)(_p + s0);                               \
      dst[ni][1] = *(const bf16x8*)(_p + s1);                               \
    }                                                                       \
  }

  // 32 MFMA on regs loaded LAST phase: no lgkm dependency on this phase
#define MFMA_HALF_FR(h, afx, bwx)                                           \
  __builtin_amdgcn_s_setprio(1);                                            \
  _Pragma("unroll")                                                         \
  for (int kk = 0; kk < 2; ++kk)                                            \
    _Pragma("unroll")                                                       \
    for (int mi = 0; mi < 4; ++mi)                                          \
      _Pragma("unroll")                                                     \
      for (int ni = 0; ni < 4; ++ni)                                        \
        acc[(h) * 4 + mi][ni] = __builtin_amdgcn_mfma_f32_16x16x32_bf16(    \
            afx[mi][kk], bwx[ni][kk], acc[(h) * 4 + mi][ni], 0, 0, 0);      \
  __builtin_amdgcn_s_setprio(0);

  // ---- prologue: stage T0 (8 loads), drain, pre-read bwP/afP, stage T1's
  //      B+A0 (6 loads -> outstanding 6 = steady-state P1-entry invariant)
  STAGE_B_ALL(0, 0);
  STAGE_A_MH0(0, 0);
  STAGE_A_MH1(0, 0);
  VMCNT0;
  BAR;
  READ_B_TO(bwP, 0);
  READ_AH_TO(afP, 0, 0);
  STAGE_B_ALL(1, 1);
  STAGE_A_MH0(1, 1);

  for (int it = 0; it < NT / 2; ++it) {
    const int U = 2 * it;                          // buf0 tile
    const int kW = (U + 2 < NT) ? U + 2 : NT - 1;  // clamped: dead-region dummy
    const int kX = (U + 3 < NT) ? U + 3 : NT - 1;

    // ---- P1: MFMA h0(U); read next (A1(U)); stage A1(V) ----
    READ_AH_TO(afQ, 0, 1);
    STAGE_A_MH1(1, U + 1);     // buf1 A1 dead since prev P3-read + barrier
    MFMA_HALF_FR(0, afP, bwP);
    VMCNT2;                    // retires B(V)+A0(V): P2 reads them
    BAR;

    // ---- P2: MFMA h1(U); read B(V)+A0(V); stage B(W)+A0(W) ----
    READ_B_TO(bwQ, 1);
    READ_AH_TO(afP, 1, 0);
    STAGE_B_ALL(0, kW);        // buf0 B+A0 dead since prev P4-read + barrier
    STAGE_A_MH0(0, kW);
    MFMA_HALF_FR(1, afQ, bwP);
    VMCNT6;                    // retires A1(V): P3 reads it
    BAR;

    // ---- P3: MFMA h0(V); read A1(V); stage A1(W) ----
    READ_AH_TO(afQ, 1, 1);
    STAGE_A_MH1(0, kW);        // buf0 A1 dead since P1-read + barrier
    MFMA_HALF_FR(0, afP, bwQ);
    VMCNT2;                    // retires B(W)+A0(W): P4 reads them
    BAR;

    // ---- P4: MFMA h1(V); read B(W)+A0(W); stage B(X)+A0(X) ----
    READ_B_TO(bwP, 0);
    READ_AH_TO(afP, 0, 0);
    STAGE_B_ALL(1, kX);        // buf1 B+A0 dead since P2-read + barrier
    STAGE_A_MH0(1, kX);
    MFMA_HALF_FR(1, afQ, bwQ);
    VMCNT6;                    // retires A1(W): next P1 reads it
    BAR;
  }

  // epilogue: D layout col = lane&15, row = quad*4 + reg  [m89-verified]
  float bv[4];
#pragma unroll
  for (int ni = 0; ni < 4; ++ni) bv[ni] = be[blockN + wn * 64 + ni * 16 + fr];

  if (EPI == 0) {
    unsigned short* Co = (unsigned short*)Cout + (long)bz * sC;
#pragma unroll
    for (int mi = 0; mi < 8; ++mi) {
      const int m = blockM + wm * 128 + mi * 16 + quad * 4;
#pragma unroll
      for (int r = 0; r < 4; ++r) {
        const long rowoff = (long)(m + r) * Nd;
#pragma unroll
        for (int ni = 0; ni < 4; ++ni) {
          float v = acc[mi][ni][r] + bv[ni];
          v = v > 0.f ? v : 0.f;
          Co[rowoff + blockN + wn * 64 + ni * 16 + fr] = f2bf(v);
        }
      }
    }
  } else {
    float* Co = (float*)Cout + (long)bz * sC;
#pragma unroll
    for (int mi = 0; mi < 8; ++mi) {
      const int m = blockM + wm * 128 + mi * 16 + quad * 4;
#pragma unroll
      for (int r = 0; r < 4; ++r) {
        const long rowoff = (long)(m + r) * Nd;
#pragma unroll
        for (int ni = 0; ni < 4; ++ni)
          Co[rowoff + blockN + wn * 64 + ni * 16 + fr] = acc[mi][ni][r] + bv[ni];
      }
    }
  }
}

// ---------------------------------------------------------------------------
extern "C" void kernel_launch(void* const* d_in, const int* in_sizes, int n_in,
                              void* d_out, int out_size, void* d_ws,
                              size_t ws_size, hipStream_t stream) {
  const float* x  = (const float*)d_in[0];
  const float* w1 = (const float*)d_in[1];
  const float* b1 = (const float*)d_in[2];
  const float* w2 = (const float*)d_in[3];
  const float* b2 = (const float*)d_in[4];
  float* out = (float*)d_out;

  const int E = 8, C = 4096, M = 1024, H = 4096, O = 1024;
  const long nx  = (long)C * M;
  const long nw1 = (long)H * M;
  const long nw2 = (long)O * H;
  const long nh  = (long)C * H;

  unsigned short* ws = (unsigned short*)d_ws;
  const size_t needBatch = (size_t)(E * (nx + nw1 + nw2 + nh)) * 2;  // 448 MiB

  if (ws_size >= needBatch) {
    unsigned short* xb  = ws;
    unsigned short* w1b = xb + E * nx;
    unsigned short* w2t = w1b + E * nw1;
    unsigned short* hb  = w2t + E * nw2;
    const long tx = E * nx, tw1 = E * nw1;
    cvt_bf16_kernel<<<tx / 1024, 256, 0, stream>>>(x, xb, tx);
    cvt_bf16_kernel<<<tw1 / 1024, 256, 0, stream>>>(w1, w1b, tw1);
    transpose_cvt_kernel<<<dim3(O / 32, H / 32, E), dim3(32, 8), 0, stream>>>(
        w2, w2t, H, O, (long)H * O, (long)O * H);
    gemm_bt_kernel<0><<<dim3(H / BN, C / BM, E), 512, 0, stream>>>(
        xb, w1b, b1, hb, H, M, nx, nw1, H, nh);
    gemm_bt_kernel<1><<<dim3(O / BN, C / BM, E), 512, 0, stream>>>(
        hb, w2t, b2, out, O, H, nh, nw2, O, (long)C * O);
  } else {
    unsigned short* xb  = ws;
    unsigned short* w1b = xb + nx;
    unsigned short* w2t = w1b + nw1;
    unsigned short* hb  = w2t + nw2;
    for (int e = 0; e < E; ++e) {
      cvt_bf16_kernel<<<nx / 1024, 256, 0, stream>>>(x + e * nx, xb, nx);
      cvt_bf16_kernel<<<nw1 / 1024, 256, 0, stream>>>(w1 + e * nw1, w1b, nw1);
      transpose_cvt_kernel<<<dim3(O / 32, H / 32, 1), dim3(32, 8), 0, stream>>>(
          w2 + e * nw2, w2t, H, O, 0, 0);
      gemm_bt_kernel<0><<<dim3(H / BN, C / BM, 1), 512, 0, stream>>>(
          xb, w1b, b1 + (long)e * H, hb, H, M, 0, 0, 0, 0);
      gemm_bt_kernel<1><<<dim3(O / BN, C / BM, 1), 512, 0, stream>>>(
          hb, w2t, b2 + (long)e * O, out + e * nx, O, H, 0, 0, 0, 0);
    }
  }
}